// Round 2
// baseline (491.957 us; speedup 1.0000x reference)
//
#include <hip/hip_runtime.h>

#define EPSV 1e-5f

constexpr int CIN = 64, NH = 128, NW = 128, HID = 384, COUT = 64;
constexpr int N1 = HID * CIN;            // 24576
constexpr int N2 = HID * 9;              // 3456
constexpr int NP = N1 + N2 + COUT * HID; // 52608

using bf16x8 = __attribute__((ext_vector_type(8))) short;
using f32x4  = __attribute__((ext_vector_type(4))) float;

__device__ __forceinline__ unsigned short f2bf(float f) {
  unsigned int u = __float_as_uint(f);
  u = (u + 0x7fffu + ((u >> 16) & 1u)) >> 16;
  return (unsigned short)u;
}
__device__ __forceinline__ unsigned int pack2(float a, float b) {
  return (unsigned int)f2bf(a) | ((unsigned int)f2bf(b) << 16);
}
__device__ __forceinline__ float ulo(unsigned int u) { return __uint_as_float(u << 16); }
__device__ __forceinline__ float uhi(unsigned int u) { return __uint_as_float(u & 0xffff0000u); }
__device__ __forceinline__ float clamp6(float v) { return fminf(fmaxf(v, 0.f), 6.f); }

// raw barrier: LDS-visibility only, never drains vmcnt (keeps prefetch in flight)
#define BAR_LDS()                                             \
  do {                                                        \
    asm volatile("s_waitcnt lgkmcnt(0)" ::: "memory");        \
    __builtin_amdgcn_s_barrier();                             \
  } while (0)

// ---------------------------------------------------------------------------
// K0: transpose x [b][c][y][x] f32 -> xT [b][y][x][c] bf16 (8.4 MB, in d_out).
// ---------------------------------------------------------------------------
__global__ __launch_bounds__(256) void k0_transpose(
    const float* __restrict__ x, unsigned short* __restrict__ xT) {
  __shared__ unsigned short xls[64][66];
  const int t = threadIdx.x;
  const int xh = blockIdx.x, y = blockIdx.y, b = blockIdx.z;
#pragma unroll
  for (int it = 0; it < 4; ++it) {
    int i = it * 256 + t;
    int xq = i & 15, c = i >> 4;
    float4 v = *reinterpret_cast<const float4*>(
        &x[((size_t)(b * CIN + c) * NH + y) * NW + xh * 64 + xq * 4]);
    *(unsigned int*)&xls[c][xq * 4]     = pack2(v.x, v.y);
    *(unsigned int*)&xls[c][xq * 4 + 2] = pack2(v.z, v.w);
  }
  __syncthreads();
#pragma unroll
  for (int it = 0; it < 4; ++it) {
    int i = it * 256 + t;
    int cq = i & 15, px = i >> 4;
    ushort4 o;
    o.x = xls[cq * 4 + 0][px];
    o.y = xls[cq * 4 + 1][px];
    o.z = xls[cq * 4 + 2][px];
    o.w = xls[cq * 4 + 3][px];
    *reinterpret_cast<ushort4*>(
        &xT[((size_t)(b * NH + y) * NW + xh * 64 + px) * 64 + cq * 4]) = o;
  }
}

// ---------------------------------------------------------------------------
// K1: per-patch pw1 (MFMA) + bn1 + relu6 -> h1T [b][y][x][hid] bf16.
// (unchanged this round; its counters will surface once k2 drops below it)
// ---------------------------------------------------------------------------
__global__ __launch_bounds__(256) void k1_pw1(
    const float* __restrict__ w, const unsigned short* __restrict__ xT,
    const float* __restrict__ g1, const float* __restrict__ b1,
    const float* __restrict__ m1, const float* __restrict__ v1,
    unsigned short* __restrict__ h1T) {
  __shared__ unsigned short Wpk[2048 * 8];  // 32 KB packed A-frags

  const unsigned int id = blockIdx.x;
  const int fbq = id & 7;
  const unsigned int rest = id >> 3;
  const int hgrp = rest % 24, q = rest / 24;
  const int fb = q * 8 + fbq;
  const int f = fb & 15, b = fb >> 4;
  const int h0 = hgrp * 16;

  const int t = threadIdx.x;
  const int lane = t & 63, wv = t >> 6;
  const int quad = lane >> 4, nn = lane & 15;
  const int pxi = wv * 16 + nn;

  // ---- stage Wpk: 16 hid x 64 c x 16 g, c-paired u32 LDS writes ----
#pragma unroll
  for (int it = 0; it < 8; ++it) {
    int i = it * 256 + t;  // 0..2047
    int gq = i & 3, cp = (i >> 2) & 31, hid = i >> 7;
    const float* wp =
        &w[((size_t)b * NP + (h0 + hid) * CIN + cp * 2) * 256 + f * 16 + gq * 4];
    float4 A  = *reinterpret_cast<const float4*>(wp);
    float4 Bv = *reinterpret_cast<const float4*>(wp + 256);
    int kc = cp >> 4, qd = (cp >> 2) & 3, j = (cp & 3) * 2;
    int hs = hid ^ (2 * qd) ^ gq;
    const float* Af = (const float*)&A;
    const float* Bf = (const float*)&Bv;
#pragma unroll
    for (int k = 0; k < 4; ++k) {
      int g = gq * 4 + k;
      *(unsigned int*)&Wpk[(((g * 2 + kc) * 4 + qd) * 16 + hs) * 8 + j] =
          pack2(Af[k], Bf[k]);
    }
  }

  float iv1[4], sh1[4];
#pragma unroll
  for (int jj = 0; jj < 4; ++jj) {
    int hid = h0 + quad * 4 + jj;
    float iv = g1[hid] * rsqrtf(v1[hid] + EPSV);
    iv1[jj] = iv;
    sh1[jj] = b1[hid] - m1[hid] * iv;
  }
  __syncthreads();  // Wpk ready; read-only below

  const int y = f * 8 + (pxi >> 3);
  const size_t rowbase = ((size_t)b * NH + y) * NW;

  for (int g = 0; g < 16; ++g) {
    const int xc = g * 8 + (pxi & 7);
    const unsigned short* xp = &xT[(rowbase + xc) * 64];
    f32x4 acc = {0.f, 0.f, 0.f, 0.f};
    const int hs = nn ^ (2 * quad) ^ (g >> 2);
#pragma unroll
    for (int kc = 0; kc < 2; ++kc) {
      bf16x8 af = *reinterpret_cast<const bf16x8*>(
          &Wpk[(((g * 2 + kc) * 4 + quad) * 16 + hs) * 8]);
      bf16x8 bfr = *reinterpret_cast<const bf16x8*>(&xp[kc * 32 + quad * 8]);
      acc = __builtin_amdgcn_mfma_f32_16x16x32_bf16(af, bfr, acc, 0, 0, 0);
    }
    ushort4 o;
    o.x = f2bf(clamp6(acc[0] * iv1[0] + sh1[0]));
    o.y = f2bf(clamp6(acc[1] * iv1[1] + sh1[1]));
    o.z = f2bf(clamp6(acc[2] * iv1[2] + sh1[2]));
    o.w = f2bf(clamp6(acc[3] * iv1[3] + sh1[3]));
    *reinterpret_cast<ushort4*>(&h1T[(rowbase + xc) * HID + h0 + quad * 4]) = o;
  }
}

// ---------------------------------------------------------------------------
// K2: dw3(reflect halo, VALU) + bn2 + relu6 + pw2 (MFMA) + bn3 + residual.
// v2 (retry — previous bench was an infra failure, not a kernel verdict):
// T14 async-stage pipeline. Chunk c+1's global loads are issued into
// registers right after chunk c's LDS writes, and land one iteration later.
// All loop barriers are raw s_barrier + lgkmcnt(0) ONLY — __syncthreads()
// would drain vmcnt(0) and serialize the prefetch (m97 barrier-drain trap).
// All staging address math hoisted out of the loop (pointer-bump only).
// dw3 / MFMA / epilogue / LDS layouts identical to the verified v1.
// ---------------------------------------------------------------------------
__global__ __launch_bounds__(256) void k2_fused(
    const float* __restrict__ x, const float* __restrict__ w,
    const float* __restrict__ g2, const float* __restrict__ b2v,
    const float* __restrict__ m2, const float* __restrict__ v2,
    const float* __restrict__ g3, const float* __restrict__ b3v,
    const float* __restrict__ m3, const float* __restrict__ v3,
    const unsigned short* __restrict__ h1T, float* __restrict__ out) {
  __shared__ unsigned short tile[10][34][40];  // 27.2 KB h1 halo [r][col][hid]
  __shared__ unsigned short h2s[256][40];      // 20.5 KB h2 chunk [px][hid]
  __shared__ unsigned short W3p[512 * 8];      // 8 KB packed A-frags
  __shared__ unsigned short k2w[4][9][40];     // 2.9 KB dw kernels [g][tap][hid]
  __shared__ float iv2s[HID], sh2s[HID];       // 3 KB

  const unsigned int id = blockIdx.x;
  const int fbq = id & 7;
  const unsigned int rest = id >> 3;
  const int gang = rest & 7, q = rest >> 3;
  const int fb = q * 8 + fbq;
  const int f = fb & 15, b = fb >> 4;
  const int gq = gang >> 1, ch = gang & 1;
  const int c0 = gq * 32;

  const int t = threadIdx.x;
  const int lane = t & 63, wv = t >> 6;
  const int quad = lane >> 4, nn = lane & 15;

  for (int i = t; i < HID; i += 256) {
    float iv = g2[i] * rsqrtf(v2[i] + EPSV);
    iv2s[i] = iv;
    sh2s[i] = b2v[i] - m2[i] * iv;
  }

  float iv3[2][4], sh3[2][4];
#pragma unroll
  for (int cot = 0; cot < 2; ++cot)
#pragma unroll
    for (int jj = 0; jj < 4; ++jj) {
      int co = ch * 32 + cot * 16 + quad * 4 + jj;
      float iv = g3[co] * rsqrtf(v3[co] + EPSV);
      iv3[cot][jj] = iv;
      sh3[cot][jj] = b3v[co] - m3[co] * iv;
    }

  f32x4 acc[2][4];
#pragma unroll
  for (int cot = 0; cot < 2; ++cot)
#pragma unroll
    for (int nt = 0; nt < 4; ++nt) acc[cot][nt] = (f32x4){0.f, 0.f, 0.f, 0.f};

  const int glt = t >> 6, rt = (t >> 3) & 7, ct = t & 7;

  // ---- hoisted staging geometry (chunk-invariant; only hb advances) ----
  // tile halo: 340 px x 4 hid-quarters, 16 B each
  const unsigned short* tsrc[6];
  unsigned short* tdst[6];
  bool tac[6];
#pragma unroll
  for (int it = 0; it < 6; ++it) {
    int idx = it * 256 + t;
    tac[it] = (idx < 1360);
    int idc = tac[it] ? idx : 0;
    int qh = idc & 3, pxid = idc >> 2;
    int r = pxid / 34, col = pxid - r * 34;
    int yy = f * 8 - 1 + r;
    yy = (yy < 0) ? -yy : ((yy > 127) ? 254 - yy : yy);
    int xc = c0 - 1 + col;
    xc = (xc < 0) ? 1 : ((xc > 127) ? 126 : xc);
    tsrc[it] = &h1T[(((size_t)b * NH + yy) * NW + xc) * HID + qh * 8];
    tdst[it] = &tile[r][col][qh * 8];
  }
  // dw kernels: param index = N1 + hb*9 + i, i = hh*9+tap
  const int hh1 = t / 9, tap1 = t - hh1 * 9;
  const float* ksrc1 = &w[((size_t)b * NP + N1 + t) * 256 + f * 16 + gq * 4];
  const bool kac2 = (t < 32);
  const int i2k = 256 + t;
  const int hh2 = i2k / 9, tap2 = i2k - hh2 * 9;
  const float* ksrc2 = &w[((size_t)b * NP + N1 + i2k) * 256 + f * 16 + gq * 4];
  // W3 A-frags
  const float* wsrc[2];
  unsigned int* wdst[2][4];
#pragma unroll
  for (int it = 0; it < 2; ++it) {
    int i = it * 256 + t;  // 0..511
    int hhp = i & 15, co = i >> 4;
    wsrc[it] = &w[((size_t)b * NP + N1 + N2 + (ch * 32 + co) * HID + hhp * 2) *
                      256 + f * 16 + gq * 4];
    int qd = (hhp * 2) >> 3, j = (hhp * 2) & 7, cot = co >> 4, cb = co & 15;
#pragma unroll
    for (int k = 0; k < 4; ++k) {
      int cop = cb ^ (2 * qd) ^ k;
      wdst[it][k] =
          (unsigned int*)&W3p[(((k * 2 + cot) * 4 + qd) * 16 + cop) * 8 + j];
    }
  }

  uint4 trg[6];
  float4 krg1, krg2;
  float4 wAr[2], wBr[2];

#define PREFETCH()                                                           \
  do {                                                                       \
    _Pragma("unroll") for (int pit = 0; pit < 6; ++pit) {                    \
      if (tac[pit]) trg[pit] = *reinterpret_cast<const uint4*>(tsrc[pit]);   \
      tsrc[pit] += 32; /* hb advance */                                      \
    }                                                                        \
    krg1 = *reinterpret_cast<const float4*>(ksrc1);                          \
    ksrc1 += 73728; /* 32*9*256 */                                           \
    if (kac2) krg2 = *reinterpret_cast<const float4*>(ksrc2);                \
    ksrc2 += 73728;                                                          \
    _Pragma("unroll") for (int pit = 0; pit < 2; ++pit) {                    \
      wAr[pit] = *reinterpret_cast<const float4*>(wsrc[pit]);                \
      wBr[pit] = *reinterpret_cast<const float4*>(wsrc[pit] + 256);          \
      wsrc[pit] += 8192; /* 32*256 */                                        \
    }                                                                        \
  } while (0)

  PREFETCH();  // chunk 0

  for (int hc = 0; hc < 12; ++hc) {
    const int hb = hc * 32;
    BAR_LDS();  // prev chunk's tile/h2s/W3p/k2w consumers done

    // ---- write staged registers -> LDS (compiler inserts the counted
    //      vmcnt wait on this chunk's loads, issued one iteration ago) ----
#pragma unroll
    for (int it = 0; it < 6; ++it)
      if (tac[it]) *reinterpret_cast<uint4*>(tdst[it]) = trg[it];
    k2w[0][tap1][hh1] = f2bf(krg1.x);
    k2w[1][tap1][hh1] = f2bf(krg1.y);
    k2w[2][tap1][hh1] = f2bf(krg1.z);
    k2w[3][tap1][hh1] = f2bf(krg1.w);
    if (kac2) {
      k2w[0][tap2][hh2] = f2bf(krg2.x);
      k2w[1][tap2][hh2] = f2bf(krg2.y);
      k2w[2][tap2][hh2] = f2bf(krg2.z);
      k2w[3][tap2][hh2] = f2bf(krg2.w);
    }
#pragma unroll
    for (int it = 0; it < 2; ++it) {
      const float* Af = (const float*)&wAr[it];
      const float* Bf = (const float*)&wBr[it];
#pragma unroll
      for (int k = 0; k < 4; ++k) *wdst[it][k] = pack2(Af[k], Bf[k]);
    }

    BAR_LDS();  // LDS staged for this chunk

    // ---- issue NEXT chunk's loads; they fly under dw3 + MFMA ----
    if (hc < 11) PREFETCH();

    // ---- dw3 + bn2 + relu6 -> h2s (thread: 1 px, 32 hids) ----
#pragma unroll
    for (int hg = 0; hg < 4; ++hg) {
      float d[8] = {0.f, 0.f, 0.f, 0.f, 0.f, 0.f, 0.f, 0.f};
#pragma unroll
      for (int dy = 0; dy < 3; ++dy)
#pragma unroll
        for (int dx = 0; dx < 3; ++dx) {
          const uint4 tv = *reinterpret_cast<const uint4*>(
              &tile[rt + dy][glt * 8 + ct + dx][hg * 8]);
          const uint4 kv =
              *reinterpret_cast<const uint4*>(&k2w[glt][dy * 3 + dx][hg * 8]);
          d[0] += ulo(tv.x) * ulo(kv.x); d[1] += uhi(tv.x) * uhi(kv.x);
          d[2] += ulo(tv.y) * ulo(kv.y); d[3] += uhi(tv.y) * uhi(kv.y);
          d[4] += ulo(tv.z) * ulo(kv.z); d[5] += uhi(tv.z) * uhi(kv.z);
          d[6] += ulo(tv.w) * ulo(kv.w); d[7] += uhi(tv.w) * uhi(kv.w);
        }
      uint4 o4;
      unsigned int op[4];
#pragma unroll
      for (int j2 = 0; j2 < 4; ++j2) {
        int ha = hb + hg * 8 + j2 * 2;
        float oa = clamp6(d[j2 * 2] * iv2s[ha] + sh2s[ha]);
        float ob = clamp6(d[j2 * 2 + 1] * iv2s[ha + 1] + sh2s[ha + 1]);
        op[j2] = (unsigned int)f2bf(oa) | ((unsigned int)f2bf(ob) << 16);
      }
      o4.x = op[0]; o4.y = op[1]; o4.z = op[2]; o4.w = op[3];
      *reinterpret_cast<uint4*>(&h2s[t][hg * 8]) = o4;
    }

    BAR_LDS();  // h2s visible

    // ---- pw2 MFMA accumulate over this 32-hid chunk (wave = patch) ----
    {
      const int gl = wv;
      const int cop = nn ^ (2 * quad) ^ gl;
      bf16x8 a0 = *reinterpret_cast<const bf16x8*>(
          &W3p[(((gl * 2 + 0) * 4 + quad) * 16 + cop) * 8]);
      bf16x8 a1 = *reinterpret_cast<const bf16x8*>(
          &W3p[(((gl * 2 + 1) * 4 + quad) * 16 + cop) * 8]);
#pragma unroll
      for (int nt = 0; nt < 4; ++nt) {
        bf16x8 bfr = *reinterpret_cast<const bf16x8*>(
            &h2s[gl * 64 + nt * 16 + nn][quad * 8]);
        acc[0][nt] = __builtin_amdgcn_mfma_f32_16x16x32_bf16(a0, bfr, acc[0][nt], 0, 0, 0);
        acc[1][nt] = __builtin_amdgcn_mfma_f32_16x16x32_bf16(a1, bfr, acc[1][nt], 0, 0, 0);
      }
    }
  }

  // ---- epilogue: bn3 + residual ----
#pragma unroll
  for (int cot = 0; cot < 2; ++cot)
#pragma unroll
    for (int nt = 0; nt < 4; ++nt) {
      int pxl = nt * 16 + nn;
      int y = f * 8 + (pxl >> 3);
      int xc = c0 + wv * 8 + (pxl & 7);
#pragma unroll
      for (int jj = 0; jj < 4; ++jj) {
        int co = ch * 32 + cot * 16 + quad * 4 + jj;
        size_t adr = ((size_t)(b * COUT + co) * NH + y) * NW + xc;
        out[adr] = acc[cot][nt][jj] * iv3[cot][jj] + sh3[cot][jj] + x[adr];
      }
    }
}

extern "C" void kernel_launch(void* const* d_in, const int* in_sizes, int n_in,
                              void* d_out, int out_size, void* d_ws,
                              size_t ws_size, hipStream_t stream) {
  (void)in_sizes; (void)n_in; (void)out_size; (void)ws_size;
  const float* x  = (const float*)d_in[0];
  const float* w  = (const float*)d_in[1];
  const float* g1 = (const float*)d_in[2];
  const float* b1 = (const float*)d_in[3];
  const float* m1 = (const float*)d_in[4];
  const float* v1 = (const float*)d_in[5];
  const float* g2 = (const float*)d_in[6];
  const float* b2 = (const float*)d_in[7];
  const float* m2 = (const float*)d_in[8];
  const float* v2 = (const float*)d_in[9];
  const float* g3 = (const float*)d_in[10];
  const float* b3 = (const float*)d_in[11];
  const float* m3 = (const float*)d_in[12];
  const float* v3 = (const float*)d_in[13];
  float* out = (float*)d_out;
  unsigned short* h1T = (unsigned short*)d_ws;  // [b][y][x][hid] bf16, 50.3 MB
  unsigned short* xT = (unsigned short*)d_out;  // [b][y][x][c] bf16, 8.4 MB
                                                // (scratch; K2 overwrites out)

  k0_transpose<<<dim3(2, 128, 4), 256, 0, stream>>>(x, xT);
  k1_pw1<<<dim3(1536), 256, 0, stream>>>(w, xT, g1, b1, m1, v1, h1T);
  k2_fused<<<dim3(512), 256, 0, stream>>>(x, w, g2, b2, m2, v2, g3, b3, m3, v3,
                                          h1T, out);
}

// Round 4
// 440.128 us; speedup vs baseline: 1.1178x; 1.1178x over previous
//
#include <hip/hip_runtime.h>

#define EPSV 1e-5f

constexpr int CIN = 64, NH = 128, NW = 128, HID = 384, COUT = 64;
constexpr int N1 = HID * CIN;            // 24576
constexpr int N2 = HID * 9;              // 3456
constexpr int NP = N1 + N2 + COUT * HID; // 52608

using bf16x8 = __attribute__((ext_vector_type(8))) short;
using f32x4  = __attribute__((ext_vector_type(4))) float;

__device__ __forceinline__ unsigned short f2bf(float f) {
  unsigned int u = __float_as_uint(f);
  u = (u + 0x7fffu + ((u >> 16) & 1u)) >> 16;
  return (unsigned short)u;
}
__device__ __forceinline__ unsigned int pack2(float a, float b) {
  return (unsigned int)f2bf(a) | ((unsigned int)f2bf(b) << 16);
}
__device__ __forceinline__ float ulo(unsigned int u) { return __uint_as_float(u << 16); }
__device__ __forceinline__ float uhi(unsigned int u) { return __uint_as_float(u & 0xffff0000u); }
__device__ __forceinline__ float clamp6(float v) { return fminf(fmaxf(v, 0.f), 6.f); }

// raw barrier: LDS-visibility only, never drains vmcnt (keeps prefetch in flight)
#define BAR_LDS()                                             \
  do {                                                        \
    asm volatile("s_waitcnt lgkmcnt(0)" ::: "memory");        \
    __builtin_amdgcn_s_barrier();                             \
  } while (0)

// ---------------------------------------------------------------------------
// K0: transpose x [b][c][y][x] f32 -> xT [b][y][x][c] bf16 (8.4 MB, in d_out).
// ---------------------------------------------------------------------------
__global__ __launch_bounds__(256) void k0_transpose(
    const float* __restrict__ x, unsigned short* __restrict__ xT) {
  __shared__ unsigned short xls[64][66];
  const int t = threadIdx.x;
  const int xh = blockIdx.x, y = blockIdx.y, b = blockIdx.z;
#pragma unroll
  for (int it = 0; it < 4; ++it) {
    int i = it * 256 + t;
    int xq = i & 15, c = i >> 4;
    float4 v = *reinterpret_cast<const float4*>(
        &x[((size_t)(b * CIN + c) * NH + y) * NW + xh * 64 + xq * 4]);
    *(unsigned int*)&xls[c][xq * 4]     = pack2(v.x, v.y);
    *(unsigned int*)&xls[c][xq * 4 + 2] = pack2(v.z, v.w);
  }
  __syncthreads();
#pragma unroll
  for (int it = 0; it < 4; ++it) {
    int i = it * 256 + t;
    int cq = i & 15, px = i >> 4;
    ushort4 o;
    o.x = xls[cq * 4 + 0][px];
    o.y = xls[cq * 4 + 1][px];
    o.z = xls[cq * 4 + 2][px];
    o.w = xls[cq * 4 + 3][px];
    *reinterpret_cast<ushort4*>(
        &xT[((size_t)(b * NH + y) * NW + xh * 64 + px) * 64 + cq * 4]) = o;
  }
}

// ---------------------------------------------------------------------------
// K1: per-patch pw1 (MFMA) + bn1 + relu6 -> h1T [b][y][x][hid] bf16.
// (unchanged; its counters will surface once k2 drops below it)
// ---------------------------------------------------------------------------
__global__ __launch_bounds__(256) void k1_pw1(
    const float* __restrict__ w, const unsigned short* __restrict__ xT,
    const float* __restrict__ g1, const float* __restrict__ b1,
    const float* __restrict__ m1, const float* __restrict__ v1,
    unsigned short* __restrict__ h1T) {
  __shared__ unsigned short Wpk[2048 * 8];  // 32 KB packed A-frags

  const unsigned int id = blockIdx.x;
  const int fbq = id & 7;
  const unsigned int rest = id >> 3;
  const int hgrp = rest % 24, q = rest / 24;
  const int fb = q * 8 + fbq;
  const int f = fb & 15, b = fb >> 4;
  const int h0 = hgrp * 16;

  const int t = threadIdx.x;
  const int lane = t & 63, wv = t >> 6;
  const int quad = lane >> 4, nn = lane & 15;
  const int pxi = wv * 16 + nn;

  // ---- stage Wpk: 16 hid x 64 c x 16 g, c-paired u32 LDS writes ----
#pragma unroll
  for (int it = 0; it < 8; ++it) {
    int i = it * 256 + t;  // 0..2047
    int gq = i & 3, cp = (i >> 2) & 31, hid = i >> 7;
    const float* wp =
        &w[((size_t)b * NP + (h0 + hid) * CIN + cp * 2) * 256 + f * 16 + gq * 4];
    float4 A  = *reinterpret_cast<const float4*>(wp);
    float4 Bv = *reinterpret_cast<const float4*>(wp + 256);
    int kc = cp >> 4, qd = (cp >> 2) & 3, j = (cp & 3) * 2;
    int hs = hid ^ (2 * qd) ^ gq;
    const float* Af = (const float*)&A;
    const float* Bf = (const float*)&Bv;
#pragma unroll
    for (int k = 0; k < 4; ++k) {
      int g = gq * 4 + k;
      *(unsigned int*)&Wpk[(((g * 2 + kc) * 4 + qd) * 16 + hs) * 8 + j] =
          pack2(Af[k], Bf[k]);
    }
  }

  float iv1[4], sh1[4];
#pragma unroll
  for (int jj = 0; jj < 4; ++jj) {
    int hid = h0 + quad * 4 + jj;
    float iv = g1[hid] * rsqrtf(v1[hid] + EPSV);
    iv1[jj] = iv;
    sh1[jj] = b1[hid] - m1[hid] * iv;
  }
  __syncthreads();  // Wpk ready; read-only below

  const int y = f * 8 + (pxi >> 3);
  const size_t rowbase = ((size_t)b * NH + y) * NW;

  for (int g = 0; g < 16; ++g) {
    const int xc = g * 8 + (pxi & 7);
    const unsigned short* xp = &xT[(rowbase + xc) * 64];
    f32x4 acc = {0.f, 0.f, 0.f, 0.f};
    const int hs = nn ^ (2 * quad) ^ (g >> 2);
#pragma unroll
    for (int kc = 0; kc < 2; ++kc) {
      bf16x8 af = *reinterpret_cast<const bf16x8*>(
          &Wpk[(((g * 2 + kc) * 4 + quad) * 16 + hs) * 8]);
      bf16x8 bfr = *reinterpret_cast<const bf16x8*>(&xp[kc * 32 + quad * 8]);
      acc = __builtin_amdgcn_mfma_f32_16x16x32_bf16(af, bfr, acc, 0, 0, 0);
    }
    ushort4 o;
    o.x = f2bf(clamp6(acc[0] * iv1[0] + sh1[0]));
    o.y = f2bf(clamp6(acc[1] * iv1[1] + sh1[1]));
    o.z = f2bf(clamp6(acc[2] * iv1[2] + sh1[2]));
    o.w = f2bf(clamp6(acc[3] * iv1[3] + sh1[3]));
    *reinterpret_cast<ushort4*>(&h1T[(rowbase + xc) * HID + h0 + quad * 4]) = o;
  }
}

// ---------------------------------------------------------------------------
// K2 v3 (retry — previous round was an infra failure, not a kernel verdict):
// same T14 async-stage pipeline as v2, but prefetch state FULLY SCALARIZED
// (no arrays -> no scratch; v2's WRITE_SIZE 146 MB was spill traffic, VGPR
// dropped to 88). Named regs tr0..tr5 / wA* / kr* and named pointer scalars
// guarantee VGPR allocation. __launch_bounds__(256,2): LDS caps us at
// 2 blocks/CU anyway, so allow up to 256 VGPRs.
// dw3 / MFMA / epilogue / LDS layouts identical to the verified v1.
// ---------------------------------------------------------------------------
__global__ __launch_bounds__(256, 2) void k2_fused(
    const float* __restrict__ x, const float* __restrict__ w,
    const float* __restrict__ g2, const float* __restrict__ b2v,
    const float* __restrict__ m2, const float* __restrict__ v2,
    const float* __restrict__ g3, const float* __restrict__ b3v,
    const float* __restrict__ m3, const float* __restrict__ v3,
    const unsigned short* __restrict__ h1T, float* __restrict__ out) {
  __shared__ unsigned short tile[10][34][40];  // 27.2 KB h1 halo [r][col][hid]
  __shared__ unsigned short h2s[256][40];      // 20.5 KB h2 chunk [px][hid]
  __shared__ unsigned short W3p[512 * 8];      // 8 KB packed A-frags
  __shared__ unsigned short k2w[4][9][40];     // 2.9 KB dw kernels [g][tap][hid]
  __shared__ float iv2s[HID], sh2s[HID];       // 3 KB

  const unsigned int id = blockIdx.x;
  const int fbq = id & 7;
  const unsigned int rest = id >> 3;
  const int gang = rest & 7, q = rest >> 3;
  const int fb = q * 8 + fbq;
  const int f = fb & 15, b = fb >> 4;
  const int gq = gang >> 1, ch = gang & 1;
  const int c0 = gq * 32;

  const int t = threadIdx.x;
  const int lane = t & 63, wv = t >> 6;
  const int quad = lane >> 4, nn = lane & 15;

  for (int i = t; i < HID; i += 256) {
    float iv = g2[i] * rsqrtf(v2[i] + EPSV);
    iv2s[i] = iv;
    sh2s[i] = b2v[i] - m2[i] * iv;
  }

  float iv3[2][4], sh3[2][4];
#pragma unroll
  for (int cot = 0; cot < 2; ++cot)
#pragma unroll
    for (int jj = 0; jj < 4; ++jj) {
      int co = ch * 32 + cot * 16 + quad * 4 + jj;
      float iv = g3[co] * rsqrtf(v3[co] + EPSV);
      iv3[cot][jj] = iv;
      sh3[cot][jj] = b3v[co] - m3[co] * iv;
    }

  f32x4 acc[2][4];
#pragma unroll
  for (int cot = 0; cot < 2; ++cot)
#pragma unroll
    for (int nt = 0; nt < 4; ++nt) acc[cot][nt] = (f32x4){0.f, 0.f, 0.f, 0.f};

  const int glt = t >> 6, rt = (t >> 3) & 7, ct = t & 7;

  // ---- hoisted staging geometry, all SCALAR (chunk-invariant) ----
  // tile halo: 1360 (px,quarter) units; slots 0..4 always active
  // (4*256+255=1279<1360), slot 5 active iff t<80.
#define TGEOM(IDX, SRC, DST)                                          \
  {                                                                   \
    int qh = (IDX) & 3, pxid = (IDX) >> 2;                            \
    int r = pxid / 34, col = pxid - r * 34;                           \
    int yy = f * 8 - 1 + r;                                           \
    yy = (yy < 0) ? -yy : ((yy > 127) ? 254 - yy : yy);               \
    int xc = c0 - 1 + col;                                            \
    xc = (xc < 0) ? 1 : ((xc > 127) ? 126 : xc);                      \
    SRC = &h1T[(((size_t)b * NH + yy) * NW + xc) * HID + qh * 8];     \
    DST = &tile[r][col][qh * 8];                                      \
  }
  const unsigned short *ts0, *ts1, *ts2, *ts3, *ts4, *ts5;
  unsigned short *td0, *td1, *td2, *td3, *td4, *td5;
  const bool tac5 = (t < 80);
  TGEOM(t, ts0, td0);
  TGEOM(256 + t, ts1, td1);
  TGEOM(512 + t, ts2, td2);
  TGEOM(768 + t, ts3, td3);
  TGEOM(1024 + t, ts4, td4);
  {
    int idx5 = tac5 ? (1280 + t) : 1359;
    TGEOM(idx5, ts5, td5);
  }
#undef TGEOM

  // dw kernels: param index = N1 + hb*9 + i, i = hh*9+tap
  const int hh1 = t / 9, tap1 = t - hh1 * 9;
  const float* ksrc1 = &w[((size_t)b * NP + N1 + t) * 256 + f * 16 + gq * 4];
  const bool kac2 = (t < 32);
  const int i2k = 256 + t;
  const int hh2 = i2k / 9, tap2 = i2k - hh2 * 9;
  const float* ksrc2 = &w[((size_t)b * NP + N1 + i2k) * 256 + f * 16 + gq * 4];

  // W3 A-frags: 2 slots x 4 k-targets, all named scalars
  const float *wsrc0, *wsrc1;
  unsigned int *wd00, *wd01, *wd02, *wd03, *wd10, *wd11, *wd12, *wd13;
#define W3GEOM(IT, SRC, D0, D1, D2, D3)                                   \
  {                                                                      \
    int i = (IT) * 256 + t;                                              \
    int hhp = i & 15, co = i >> 4;                                       \
    SRC = &w[((size_t)b * NP + N1 + N2 + (ch * 32 + co) * HID + hhp * 2) * \
                 256 + f * 16 + gq * 4];                                 \
    int qd = (hhp * 2) >> 3, j = (hhp * 2) & 7, cot = co >> 4,           \
        cb = co & 15;                                                    \
    D0 = (unsigned int*)&W3p[(((0 * 2 + cot) * 4 + qd) * 16 +            \
                              (cb ^ (2 * qd) ^ 0)) * 8 + j];             \
    D1 = (unsigned int*)&W3p[(((1 * 2 + cot) * 4 + qd) * 16 +            \
                              (cb ^ (2 * qd) ^ 1)) * 8 + j];             \
    D2 = (unsigned int*)&W3p[(((2 * 2 + cot) * 4 + qd) * 16 +            \
                              (cb ^ (2 * qd) ^ 2)) * 8 + j];             \
    D3 = (unsigned int*)&W3p[(((3 * 2 + cot) * 4 + qd) * 16 +            \
                              (cb ^ (2 * qd) ^ 3)) * 8 + j];             \
  }
  W3GEOM(0, wsrc0, wd00, wd01, wd02, wd03);
  W3GEOM(1, wsrc1, wd10, wd11, wd12, wd13);
#undef W3GEOM

  uint4 tr0, tr1, tr2, tr3, tr4, tr5;
  float4 kr1, kr2;
  float4 wA0, wB0, wA1, wB1;

#define PREFETCH()                                                  \
  do {                                                              \
    tr0 = *reinterpret_cast<const uint4*>(ts0); ts0 += 32;          \
    tr1 = *reinterpret_cast<const uint4*>(ts1); ts1 += 32;          \
    tr2 = *reinterpret_cast<const uint4*>(ts2); ts2 += 32;          \
    tr3 = *reinterpret_cast<const uint4*>(ts3); ts3 += 32;          \
    tr4 = *reinterpret_cast<const uint4*>(ts4); ts4 += 32;          \
    if (tac5) tr5 = *reinterpret_cast<const uint4*>(ts5);           \
    ts5 += 32;                                                      \
    kr1 = *reinterpret_cast<const float4*>(ksrc1); ksrc1 += 73728;  \
    if (kac2) kr2 = *reinterpret_cast<const float4*>(ksrc2);        \
    ksrc2 += 73728;                                                 \
    wA0 = *reinterpret_cast<const float4*>(wsrc0);                  \
    wB0 = *reinterpret_cast<const float4*>(wsrc0 + 256);            \
    wsrc0 += 8192;                                                  \
    wA1 = *reinterpret_cast<const float4*>(wsrc1);                  \
    wB1 = *reinterpret_cast<const float4*>(wsrc1 + 256);            \
    wsrc1 += 8192;                                                  \
  } while (0)

  tr5 = (uint4){0u, 0u, 0u, 0u};
  kr2 = (float4){0.f, 0.f, 0.f, 0.f};
  PREFETCH();  // chunk 0

  for (int hc = 0; hc < 12; ++hc) {
    const int hb = hc * 32;
    BAR_LDS();  // prev chunk consumers done with tile/W3p/k2w/h2s

    // ---- write staged registers -> LDS (compiler inserts the counted
    //      vmcnt wait on this chunk's loads, issued one iteration ago) ----
    *reinterpret_cast<uint4*>(td0) = tr0;
    *reinterpret_cast<uint4*>(td1) = tr1;
    *reinterpret_cast<uint4*>(td2) = tr2;
    *reinterpret_cast<uint4*>(td3) = tr3;
    *reinterpret_cast<uint4*>(td4) = tr4;
    if (tac5) *reinterpret_cast<uint4*>(td5) = tr5;
    k2w[0][tap1][hh1] = f2bf(kr1.x);
    k2w[1][tap1][hh1] = f2bf(kr1.y);
    k2w[2][tap1][hh1] = f2bf(kr1.z);
    k2w[3][tap1][hh1] = f2bf(kr1.w);
    if (kac2) {
      k2w[0][tap2][hh2] = f2bf(kr2.x);
      k2w[1][tap2][hh2] = f2bf(kr2.y);
      k2w[2][tap2][hh2] = f2bf(kr2.z);
      k2w[3][tap2][hh2] = f2bf(kr2.w);
    }
    *wd00 = pack2(wA0.x, wB0.x);
    *wd01 = pack2(wA0.y, wB0.y);
    *wd02 = pack2(wA0.z, wB0.z);
    *wd03 = pack2(wA0.w, wB0.w);
    *wd10 = pack2(wA1.x, wB1.x);
    *wd11 = pack2(wA1.y, wB1.y);
    *wd12 = pack2(wA1.z, wB1.z);
    *wd13 = pack2(wA1.w, wB1.w);

    BAR_LDS();  // LDS staged for this chunk

    // ---- issue NEXT chunk's loads; they fly under dw3 + MFMA ----
    if (hc < 11) PREFETCH();

    // ---- dw3 + bn2 + relu6 -> h2s (thread: 1 px, 32 hids) ----
#pragma unroll
    for (int hg = 0; hg < 4; ++hg) {
      float d[8] = {0.f, 0.f, 0.f, 0.f, 0.f, 0.f, 0.f, 0.f};
#pragma unroll
      for (int dy = 0; dy < 3; ++dy)
#pragma unroll
        for (int dx = 0; dx < 3; ++dx) {
          const uint4 tv = *reinterpret_cast<const uint4*>(
              &tile[rt + dy][glt * 8 + ct + dx][hg * 8]);
          const uint4 kv =
              *reinterpret_cast<const uint4*>(&k2w[glt][dy * 3 + dx][hg * 8]);
          d[0] += ulo(tv.x) * ulo(kv.x); d[1] += uhi(tv.x) * uhi(kv.x);
          d[2] += ulo(tv.y) * ulo(kv.y); d[3] += uhi(tv.y) * uhi(kv.y);
          d[4] += ulo(tv.z) * ulo(kv.z); d[5] += uhi(tv.z) * uhi(kv.z);
          d[6] += ulo(tv.w) * ulo(kv.w); d[7] += uhi(tv.w) * uhi(kv.w);
        }
      uint4 o4;
      unsigned int op[4];
#pragma unroll
      for (int j2 = 0; j2 < 4; ++j2) {
        int ha = hb + hg * 8 + j2 * 2;
        float oa = clamp6(d[j2 * 2] * iv2s[ha] + sh2s[ha]);
        float ob = clamp6(d[j2 * 2 + 1] * iv2s[ha + 1] + sh2s[ha + 1]);
        op[j2] = (unsigned int)f2bf(oa) | ((unsigned int)f2bf(ob) << 16);
      }
      o4.x = op[0]; o4.y = op[1]; o4.z = op[2]; o4.w = op[3];
      *reinterpret_cast<uint4*>(&h2s[t][hg * 8]) = o4;
    }

    BAR_LDS();  // h2s visible

    // ---- pw2 MFMA accumulate over this 32-hid chunk (wave = patch) ----
    {
      const int gl = wv;
      const int cop = nn ^ (2 * quad) ^ gl;
      bf16x8 a0 = *reinterpret_cast<const bf16x8*>(
          &W3p[(((gl * 2 + 0) * 4 + quad) * 16 + cop) * 8]);
      bf16x8 a1 = *reinterpret_cast<const bf16x8*>(
          &W3p[(((gl * 2 + 1) * 4 + quad) * 16 + cop) * 8]);
#pragma unroll
      for (int nt = 0; nt < 4; ++nt) {
        bf16x8 bfr = *reinterpret_cast<const bf16x8*>(
            &h2s[gl * 64 + nt * 16 + nn][quad * 8]);
        acc[0][nt] = __builtin_amdgcn_mfma_f32_16x16x32_bf16(a0, bfr, acc[0][nt], 0, 0, 0);
        acc[1][nt] = __builtin_amdgcn_mfma_f32_16x16x32_bf16(a1, bfr, acc[1][nt], 0, 0, 0);
      }
    }
  }

  // ---- epilogue: bn3 + residual ----
#pragma unroll
  for (int cot = 0; cot < 2; ++cot)
#pragma unroll
    for (int nt = 0; nt < 4; ++nt) {
      int pxl = nt * 16 + nn;
      int y = f * 8 + (pxl >> 3);
      int xc = c0 + wv * 8 + (pxl & 7);
#pragma unroll
      for (int jj = 0; jj < 4; ++jj) {
        int co = ch * 32 + cot * 16 + quad * 4 + jj;
        size_t adr = ((size_t)(b * COUT + co) * NH + y) * NW + xc;
        out[adr] = acc[cot][nt][jj] * iv3[cot][jj] + sh3[cot][jj] + x[adr];
      }
    }
}

extern "C" void kernel_launch(void* const* d_in, const int* in_sizes, int n_in,
                              void* d_out, int out_size, void* d_ws,
                              size_t ws_size, hipStream_t stream) {
  (void)in_sizes; (void)n_in; (void)out_size; (void)ws_size;
  const float* x  = (const float*)d_in[0];
  const float* w  = (const float*)d_in[1];
  const float* g1 = (const float*)d_in[2];
  const float* b1 = (const float*)d_in[3];
  const float* m1 = (const float*)d_in[4];
  const float* v1 = (const float*)d_in[5];
  const float* g2 = (const float*)d_in[6];
  const float* b2 = (const float*)d_in[7];
  const float* m2 = (const float*)d_in[8];
  const float* v2 = (const float*)d_in[9];
  const float* g3 = (const float*)d_in[10];
  const float* b3 = (const float*)d_in[11];
  const float* m3 = (const float*)d_in[12];
  const float* v3 = (const float*)d_in[13];
  float* out = (float*)d_out;
  unsigned short* h1T = (unsigned short*)d_ws;  // [b][y][x][hid] bf16, 50.3 MB
  unsigned short* xT = (unsigned short*)d_out;  // [b][y][x][c] bf16, 8.4 MB
                                                // (scratch; K2 overwrites out)

  k0_transpose<<<dim3(2, 128, 4), 256, 0, stream>>>(x, xT);
  k1_pw1<<<dim3(1536), 256, 0, stream>>>(w, xT, g1, b1, m1, v1, h1T);
  k2_fused<<<dim3(512), 256, 0, stream>>>(x, w, g2, b2, m2, v2, g3, b3, m3, v3,
                                          h1T, out);
}

// Round 5
// 439.842 us; speedup vs baseline: 1.1185x; 1.0006x over previous
//
#include <hip/hip_runtime.h>

#define EPSV 1e-5f

constexpr int CIN = 64, NH = 128, NW = 128, HID = 384, COUT = 64;
constexpr int N1 = HID * CIN;            // 24576
constexpr int N2 = HID * 9;              // 3456
constexpr int NP = N1 + N2 + COUT * HID; // 52608

using bf16x8 = __attribute__((ext_vector_type(8))) short;
using f32x4  = __attribute__((ext_vector_type(4))) float;

__device__ __forceinline__ unsigned short f2bf(float f) {
  unsigned int u = __float_as_uint(f);
  u = (u + 0x7fffu + ((u >> 16) & 1u)) >> 16;
  return (unsigned short)u;
}
__device__ __forceinline__ unsigned int pack2(float a, float b) {
  return (unsigned int)f2bf(a) | ((unsigned int)f2bf(b) << 16);
}
__device__ __forceinline__ float ulo(unsigned int u) { return __uint_as_float(u << 16); }
__device__ __forceinline__ float uhi(unsigned int u) { return __uint_as_float(u & 0xffff0000u); }
__device__ __forceinline__ float clamp6(float v) { return fminf(fmaxf(v, 0.f), 6.f); }

// raw barrier: LDS-visibility only, never drains vmcnt (keeps prefetch in flight)
#define BAR_LDS()                                             \
  do {                                                        \
    asm volatile("s_waitcnt lgkmcnt(0)" ::: "memory");        \
    __builtin_amdgcn_s_barrier();                             \
  } while (0)

// ---------------------------------------------------------------------------
// K0: transpose x [b][c][y][x] f32 -> xT [b][y][x][c] bf16 (8.4 MB, in d_out).
// ---------------------------------------------------------------------------
__global__ __launch_bounds__(256) void k0_transpose(
    const float* __restrict__ x, unsigned short* __restrict__ xT) {
  __shared__ unsigned short xls[64][66];
  const int t = threadIdx.x;
  const int xh = blockIdx.x, y = blockIdx.y, b = blockIdx.z;
#pragma unroll
  for (int it = 0; it < 4; ++it) {
    int i = it * 256 + t;
    int xq = i & 15, c = i >> 4;
    float4 v = *reinterpret_cast<const float4*>(
        &x[((size_t)(b * CIN + c) * NH + y) * NW + xh * 64 + xq * 4]);
    *(unsigned int*)&xls[c][xq * 4]     = pack2(v.x, v.y);
    *(unsigned int*)&xls[c][xq * 4 + 2] = pack2(v.z, v.w);
  }
  __syncthreads();
#pragma unroll
  for (int it = 0; it < 4; ++it) {
    int i = it * 256 + t;
    int cq = i & 15, px = i >> 4;
    ushort4 o;
    o.x = xls[cq * 4 + 0][px];
    o.y = xls[cq * 4 + 1][px];
    o.z = xls[cq * 4 + 2][px];
    o.w = xls[cq * 4 + 3][px];
    *reinterpret_cast<ushort4*>(
        &xT[((size_t)(b * NH + y) * NW + xh * 64 + px) * 64 + cq * 4]) = o;
  }
}

// ---------------------------------------------------------------------------
// K1: per-patch pw1 (MFMA) + bn1 + relu6 -> h1T [b][y][x][hid] bf16.
// (unchanged; with k2 dropping it should surface in top-5 next round)
// ---------------------------------------------------------------------------
__global__ __launch_bounds__(256) void k1_pw1(
    const float* __restrict__ w, const unsigned short* __restrict__ xT,
    const float* __restrict__ g1, const float* __restrict__ b1,
    const float* __restrict__ m1, const float* __restrict__ v1,
    unsigned short* __restrict__ h1T) {
  __shared__ unsigned short Wpk[2048 * 8];  // 32 KB packed A-frags

  const unsigned int id = blockIdx.x;
  const int fbq = id & 7;
  const unsigned int rest = id >> 3;
  const int hgrp = rest % 24, q = rest / 24;
  const int fb = q * 8 + fbq;
  const int f = fb & 15, b = fb >> 4;
  const int h0 = hgrp * 16;

  const int t = threadIdx.x;
  const int lane = t & 63, wv = t >> 6;
  const int quad = lane >> 4, nn = lane & 15;
  const int pxi = wv * 16 + nn;

  // ---- stage Wpk: 16 hid x 64 c x 16 g, c-paired u32 LDS writes ----
#pragma unroll
  for (int it = 0; it < 8; ++it) {
    int i = it * 256 + t;  // 0..2047
    int gq = i & 3, cp = (i >> 2) & 31, hid = i >> 7;
    const float* wp =
        &w[((size_t)b * NP + (h0 + hid) * CIN + cp * 2) * 256 + f * 16 + gq * 4];
    float4 A  = *reinterpret_cast<const float4*>(wp);
    float4 Bv = *reinterpret_cast<const float4*>(wp + 256);
    int kc = cp >> 4, qd = (cp >> 2) & 3, j = (cp & 3) * 2;
    int hs = hid ^ (2 * qd) ^ gq;
    const float* Af = (const float*)&A;
    const float* Bf = (const float*)&Bv;
#pragma unroll
    for (int k = 0; k < 4; ++k) {
      int g = gq * 4 + k;
      *(unsigned int*)&Wpk[(((g * 2 + kc) * 4 + qd) * 16 + hs) * 8 + j] =
          pack2(Af[k], Bf[k]);
    }
  }

  float iv1[4], sh1[4];
#pragma unroll
  for (int jj = 0; jj < 4; ++jj) {
    int hid = h0 + quad * 4 + jj;
    float iv = g1[hid] * rsqrtf(v1[hid] + EPSV);
    iv1[jj] = iv;
    sh1[jj] = b1[hid] - m1[hid] * iv;
  }
  __syncthreads();  // Wpk ready; read-only below

  const int y = f * 8 + (pxi >> 3);
  const size_t rowbase = ((size_t)b * NH + y) * NW;

  for (int g = 0; g < 16; ++g) {
    const int xc = g * 8 + (pxi & 7);
    const unsigned short* xp = &xT[(rowbase + xc) * 64];
    f32x4 acc = {0.f, 0.f, 0.f, 0.f};
    const int hs = nn ^ (2 * quad) ^ (g >> 2);
#pragma unroll
    for (int kc = 0; kc < 2; ++kc) {
      bf16x8 af = *reinterpret_cast<const bf16x8*>(
          &Wpk[(((g * 2 + kc) * 4 + quad) * 16 + hs) * 8]);
      bf16x8 bfr = *reinterpret_cast<const bf16x8*>(&xp[kc * 32 + quad * 8]);
      acc = __builtin_amdgcn_mfma_f32_16x16x32_bf16(af, bfr, acc, 0, 0, 0);
    }
    ushort4 o;
    o.x = f2bf(clamp6(acc[0] * iv1[0] + sh1[0]));
    o.y = f2bf(clamp6(acc[1] * iv1[1] + sh1[1]));
    o.z = f2bf(clamp6(acc[2] * iv1[2] + sh1[2]));
    o.w = f2bf(clamp6(acc[3] * iv1[3] + sh1[3]));
    *reinterpret_cast<ushort4*>(&h1T[(rowbase + xc) * HID + h0 + quad * 4]) = o;
  }
}

// ---------------------------------------------------------------------------
// K2 v4: ch-split MERGED. 256 blocks x 512 threads; block = (f,b,gq) covers
// 8 rows x 32 cols x ALL 64 co. v3's ch=0/1 blocks duplicated the h1T halo
// fetch AND the whole dw3 compute (they only split output channels); merging
// halves per-CU dw3 VALU and h1T fetch (~195 -> ~125 MB). 8 waves/block =
// 8 waves/CU (same as v3's 2x4). W3p doubles to 16 KB (both co halves);
// wave = (coh, gl). All verified sub-layouts and the T14 scalar-prefetch
// pipeline (v3, WRITE_SIZE-verified no-spill) are unchanged.
// ---------------------------------------------------------------------------
__global__ __launch_bounds__(512, 2) void k2_fused(
    const float* __restrict__ x, const float* __restrict__ w,
    const float* __restrict__ g2, const float* __restrict__ b2v,
    const float* __restrict__ m2, const float* __restrict__ v2,
    const float* __restrict__ g3, const float* __restrict__ b3v,
    const float* __restrict__ m3, const float* __restrict__ v3,
    const unsigned short* __restrict__ h1T, float* __restrict__ out) {
  __shared__ unsigned short tile[10][34][40];  // 27.2 KB h1 halo [r][col][hid]
  __shared__ unsigned short h2s[256][40];      // 20.5 KB h2 chunk [px][hid]
  __shared__ unsigned short W3p[2 * 4096];     // 16 KB packed A-frags (2 coh)
  __shared__ unsigned short k2w[4][9][40];     // 2.9 KB dw kernels [g][tap][hid]
  __shared__ float iv2s[HID], sh2s[HID];       // 3 KB              (70.0 KB tot)

  const unsigned int id = blockIdx.x;          // 256 blocks, 1 per CU
  const int fbq = id & 7;                      // XCD
  const unsigned int rest = id >> 3;           // 0..31
  const int gq = rest & 3, q = rest >> 2;      // col-group, fb-chunk
  const int fb = q * 8 + fbq;
  const int f = fb & 15, b = fb >> 4;
  const int c0 = gq * 32;

  const int t = threadIdx.x;                   // 0..511
  const int lane = t & 63;
  const int quad = lane >> 4, nn = lane & 15;

  for (int i = t; i < HID; i += 512) {
    float iv = g2[i] * rsqrtf(v2[i] + EPSV);
    iv2s[i] = iv;
    sh2s[i] = b2v[i] - m2[i] * iv;
  }

  // MFMA wave roles: wave = (coh, gl)
  const int wv = t >> 6;                       // 0..7
  const int gl = wv & 3, coh = wv >> 2;

  float iv3[2][4], sh3[2][4];
#pragma unroll
  for (int cot = 0; cot < 2; ++cot)
#pragma unroll
    for (int jj = 0; jj < 4; ++jj) {
      int co = coh * 32 + cot * 16 + quad * 4 + jj;
      float iv = g3[co] * rsqrtf(v3[co] + EPSV);
      iv3[cot][jj] = iv;
      sh3[cot][jj] = b3v[co] - m3[co] * iv;
    }

  f32x4 acc[2][4];
#pragma unroll
  for (int cot = 0; cot < 2; ++cot)
#pragma unroll
    for (int nt = 0; nt < 4; ++nt) acc[cot][nt] = (f32x4){0.f, 0.f, 0.f, 0.f};

  // dw3 roles: thread -> (px, hid-half)
  const int px = t & 255, half = t >> 8;
  const int glt = px >> 6, rt = (px >> 3) & 7, ct = px & 7;

  // ---- hoisted staging geometry, all SCALAR (chunk-invariant) ----
  // tile halo: 1360 (px,quarter) units over 512 threads: slots 0,1 full,
  // slot 2 active iff t<336.
#define TGEOM(IDX, SRC, DST)                                          \
  {                                                                   \
    int qh = (IDX) & 3, pxid = (IDX) >> 2;                            \
    int r = pxid / 34, col = pxid - r * 34;                           \
    int yy = f * 8 - 1 + r;                                           \
    yy = (yy < 0) ? -yy : ((yy > 127) ? 254 - yy : yy);               \
    int xc = c0 - 1 + col;                                            \
    xc = (xc < 0) ? 1 : ((xc > 127) ? 126 : xc);                      \
    SRC = &h1T[(((size_t)b * NH + yy) * NW + xc) * HID + qh * 8];     \
    DST = &tile[r][col][qh * 8];                                      \
  }
  const unsigned short *ts0, *ts1, *ts2;
  unsigned short *td0, *td1, *td2;
  const bool tac2 = (t < 336);
  TGEOM(t, ts0, td0);
  TGEOM(512 + t, ts1, td1);
  {
    int idx2 = tac2 ? (1024 + t) : 1359;
    TGEOM(idx2, ts2, td2);
  }
#undef TGEOM

  // dw kernels: 288 units, single slot, active iff t<288
  const bool kac1 = (t < 288);
  const int tk = kac1 ? t : 287;
  const int hh1 = tk / 9, tap1 = tk - hh1 * 9;
  const float* ksrc1 = &w[((size_t)b * NP + N1 + tk) * 256 + f * 16 + gq * 4];

  // W3 A-frags: 1024 units (64 co x 16 hhp) over 512 threads: 2 slots
  const float *wsrc0, *wsrc1;
  unsigned int *wd00, *wd01, *wd02, *wd03, *wd10, *wd11, *wd12, *wd13;
#define W3GEOM(IT, SRC, D0, D1, D2, D3)                                    \
  {                                                                        \
    int i = (IT) * 512 + t;                                                \
    int hhp = i & 15, co = i >> 4; /* co 0..63 */                          \
    SRC = &w[((size_t)b * NP + N1 + N2 + co * HID + hhp * 2) * 256 +       \
             f * 16 + gq * 4];                                             \
    int qd = (hhp * 2) >> 3, j = (hhp * 2) & 7;                            \
    int ch2 = co >> 5, cot = (co >> 4) & 1, cb = co & 15;                  \
    D0 = (unsigned int*)&W3p[ch2 * 4096 +                                  \
                             (((0 * 2 + cot) * 4 + qd) * 16 +              \
                              (cb ^ (2 * qd) ^ 0)) * 8 + j];               \
    D1 = (unsigned int*)&W3p[ch2 * 4096 +                                  \
                             (((1 * 2 + cot) * 4 + qd) * 16 +              \
                              (cb ^ (2 * qd) ^ 1)) * 8 + j];               \
    D2 = (unsigned int*)&W3p[ch2 * 4096 +                                  \
                             (((2 * 2 + cot) * 4 + qd) * 16 +              \
                              (cb ^ (2 * qd) ^ 2)) * 8 + j];               \
    D3 = (unsigned int*)&W3p[ch2 * 4096 +                                  \
                             (((3 * 2 + cot) * 4 + qd) * 16 +              \
                              (cb ^ (2 * qd) ^ 3)) * 8 + j];               \
  }
  W3GEOM(0, wsrc0, wd00, wd01, wd02, wd03);
  W3GEOM(1, wsrc1, wd10, wd11, wd12, wd13);
#undef W3GEOM

  uint4 tr0, tr1, tr2;
  float4 kr1;
  float4 wA0, wB0, wA1, wB1;

#define PREFETCH()                                                  \
  do {                                                              \
    tr0 = *reinterpret_cast<const uint4*>(ts0); ts0 += 32;          \
    tr1 = *reinterpret_cast<const uint4*>(ts1); ts1 += 32;          \
    if (tac2) tr2 = *reinterpret_cast<const uint4*>(ts2);           \
    ts2 += 32;                                                      \
    if (kac1) kr1 = *reinterpret_cast<const float4*>(ksrc1);        \
    ksrc1 += 73728; /* 32*9*256 */                                  \
    wA0 = *reinterpret_cast<const float4*>(wsrc0);                  \
    wB0 = *reinterpret_cast<const float4*>(wsrc0 + 256);            \
    wsrc0 += 8192; /* 32*256 */                                     \
    wA1 = *reinterpret_cast<const float4*>(wsrc1);                  \
    wB1 = *reinterpret_cast<const float4*>(wsrc1 + 256);            \
    wsrc1 += 8192;                                                  \
  } while (0)

  tr2 = (uint4){0u, 0u, 0u, 0u};
  kr1 = (float4){0.f, 0.f, 0.f, 0.f};
  PREFETCH();  // chunk 0

  for (int hc = 0; hc < 12; ++hc) {
    const int hb = hc * 32;
    BAR_LDS();  // prev chunk consumers done with tile/W3p/k2w/h2s

    // ---- write staged registers -> LDS (counted vmcnt wait on this
    //      chunk's loads, issued one iteration ago) ----
    *reinterpret_cast<uint4*>(td0) = tr0;
    *reinterpret_cast<uint4*>(td1) = tr1;
    if (tac2) *reinterpret_cast<uint4*>(td2) = tr2;
    if (kac1) {
      k2w[0][tap1][hh1] = f2bf(kr1.x);
      k2w[1][tap1][hh1] = f2bf(kr1.y);
      k2w[2][tap1][hh1] = f2bf(kr1.z);
      k2w[3][tap1][hh1] = f2bf(kr1.w);
    }
    *wd00 = pack2(wA0.x, wB0.x);
    *wd01 = pack2(wA0.y, wB0.y);
    *wd02 = pack2(wA0.z, wB0.z);
    *wd03 = pack2(wA0.w, wB0.w);
    *wd10 = pack2(wA1.x, wB1.x);
    *wd11 = pack2(wA1.y, wB1.y);
    *wd12 = pack2(wA1.z, wB1.z);
    *wd13 = pack2(wA1.w, wB1.w);

    BAR_LDS();  // LDS staged for this chunk

    // ---- issue NEXT chunk's loads; they fly under dw3 + MFMA ----
    if (hc < 11) PREFETCH();

    // ---- dw3 + bn2 + relu6 -> h2s (thread: 1 px, 16 hids = 2 hg) ----
#pragma unroll
    for (int hg2 = 0; hg2 < 2; ++hg2) {
      const int hg = half * 2 + hg2;
      float d[8] = {0.f, 0.f, 0.f, 0.f, 0.f, 0.f, 0.f, 0.f};
#pragma unroll
      for (int dy = 0; dy < 3; ++dy)
#pragma unroll
        for (int dx = 0; dx < 3; ++dx) {
          const uint4 tv = *reinterpret_cast<const uint4*>(
              &tile[rt + dy][glt * 8 + ct + dx][hg * 8]);
          const uint4 kv =
              *reinterpret_cast<const uint4*>(&k2w[glt][dy * 3 + dx][hg * 8]);
          d[0] += ulo(tv.x) * ulo(kv.x); d[1] += uhi(tv.x) * uhi(kv.x);
          d[2] += ulo(tv.y) * ulo(kv.y); d[3] += uhi(tv.y) * uhi(kv.y);
          d[4] += ulo(tv.z) * ulo(kv.z); d[5] += uhi(tv.z) * uhi(kv.z);
          d[6] += ulo(tv.w) * ulo(kv.w); d[7] += uhi(tv.w) * uhi(kv.w);
        }
      uint4 o4;
      unsigned int op[4];
#pragma unroll
      for (int j2 = 0; j2 < 4; ++j2) {
        int ha = hb + hg * 8 + j2 * 2;
        float oa = clamp6(d[j2 * 2] * iv2s[ha] + sh2s[ha]);
        float ob = clamp6(d[j2 * 2 + 1] * iv2s[ha + 1] + sh2s[ha + 1]);
        op[j2] = (unsigned int)f2bf(oa) | ((unsigned int)f2bf(ob) << 16);
      }
      o4.x = op[0]; o4.y = op[1]; o4.z = op[2]; o4.w = op[3];
      *reinterpret_cast<uint4*>(&h2s[px][hg * 8]) = o4;
    }

    BAR_LDS();  // h2s visible

    // ---- pw2 MFMA accumulate over this 32-hid chunk ----
    // wave (coh, gl): A from W3p half coh, B = h2s rows of px-group gl.
    {
      const int cop = nn ^ (2 * quad) ^ gl;
      bf16x8 a0 = *reinterpret_cast<const bf16x8*>(
          &W3p[coh * 4096 + (((gl * 2 + 0) * 4 + quad) * 16 + cop) * 8]);
      bf16x8 a1 = *reinterpret_cast<const bf16x8*>(
          &W3p[coh * 4096 + (((gl * 2 + 1) * 4 + quad) * 16 + cop) * 8]);
#pragma unroll
      for (int nt = 0; nt < 4; ++nt) {
        bf16x8 bfr = *reinterpret_cast<const bf16x8*>(
            &h2s[gl * 64 + nt * 16 + nn][quad * 8]);
        acc[0][nt] = __builtin_amdgcn_mfma_f32_16x16x32_bf16(a0, bfr, acc[0][nt], 0, 0, 0);
        acc[1][nt] = __builtin_amdgcn_mfma_f32_16x16x32_bf16(a1, bfr, acc[1][nt], 0, 0, 0);
      }
    }
  }

  // ---- epilogue: bn3 + residual ----
#pragma unroll
  for (int cot = 0; cot < 2; ++cot)
#pragma unroll
    for (int nt = 0; nt < 4; ++nt) {
      int pxl = nt * 16 + nn;
      int y = f * 8 + (pxl >> 3);
      int xc = c0 + gl * 8 + (pxl & 7);
#pragma unroll
      for (int jj = 0; jj < 4; ++jj) {
        int co = coh * 32 + cot * 16 + quad * 4 + jj;
        size_t adr = ((size_t)(b * COUT + co) * NH + y) * NW + xc;
        out[adr] = acc[cot][nt][jj] * iv3[cot][jj] + sh3[cot][jj] + x[adr];
      }
    }
}

extern "C" void kernel_launch(void* const* d_in, const int* in_sizes, int n_in,
                              void* d_out, int out_size, void* d_ws,
                              size_t ws_size, hipStream_t stream) {
  (void)in_sizes; (void)n_in; (void)out_size; (void)ws_size;
  const float* x  = (const float*)d_in[0];
  const float* w  = (const float*)d_in[1];
  const float* g1 = (const float*)d_in[2];
  const float* b1 = (const float*)d_in[3];
  const float* m1 = (const float*)d_in[4];
  const float* v1 = (const float*)d_in[5];
  const float* g2 = (const float*)d_in[6];
  const float* b2 = (const float*)d_in[7];
  const float* m2 = (const float*)d_in[8];
  const float* v2 = (const float*)d_in[9];
  const float* g3 = (const float*)d_in[10];
  const float* b3 = (const float*)d_in[11];
  const float* m3 = (const float*)d_in[12];
  const float* v3 = (const float*)d_in[13];
  float* out = (float*)d_out;
  unsigned short* h1T = (unsigned short*)d_ws;  // [b][y][x][hid] bf16, 50.3 MB
  unsigned short* xT = (unsigned short*)d_out;  // [b][y][x][c] bf16, 8.4 MB
                                                // (scratch; K2 overwrites out)

  k0_transpose<<<dim3(2, 128, 4), 256, 0, stream>>>(x, xT);
  k1_pw1<<<dim3(1536), 256, 0, stream>>>(w, xT, g1, b1, m1, v1, h1T);
  k2_fused<<<dim3(256), 512, 0, stream>>>(x, w, g2, b2, m2, v2, g3, b3, m3, v3,
                                          h1T, out);
}

// Round 7
// 431.333 us; speedup vs baseline: 1.1405x; 1.0197x over previous
//
#include <hip/hip_runtime.h>

#define EPSV 1e-5f

constexpr int CIN = 64, NH = 128, NW = 128, HID = 384, COUT = 64;
constexpr int N1 = HID * CIN;            // 24576
constexpr int N2 = HID * 9;              // 3456
constexpr int NP = N1 + N2 + COUT * HID; // 52608

using bf16x8 = __attribute__((ext_vector_type(8))) short;
using f32x4  = __attribute__((ext_vector_type(4))) float;
using h16x2  = __attribute__((ext_vector_type(2))) _Float16;
using f16x8  = __attribute__((ext_vector_type(8))) _Float16;

__device__ __forceinline__ unsigned short f2bf(float f) {
  unsigned int u = __float_as_uint(f);
  u = (u + 0x7fffu + ((u >> 16) & 1u)) >> 16;
  return (unsigned short)u;
}
__device__ __forceinline__ unsigned int pack2(float a, float b) {
  return (unsigned int)f2bf(a) | ((unsigned int)f2bf(b) << 16);
}
// fp16 helpers: v_cvt_pkrtz_f16_f32 packs 2 f32 -> 2 f16 in ONE instruction.
// NOTE: the builtin returns an __fp16 ext-vector (not _Float16) — take it
// with auto and bit-reinterpret, never name its element type (r6 fix).
__device__ __forceinline__ unsigned int pkh2(float a, float b) {
  auto h = __builtin_amdgcn_cvt_pkrtz(a, b);
  return *reinterpret_cast<unsigned int*>(&h);
}
__device__ __forceinline__ unsigned short f2h(float f) {
  _Float16 h = (_Float16)f;
  return *reinterpret_cast<unsigned short*>(&h);
}
__device__ __forceinline__ h16x2 uh2(unsigned int u) {
  return *reinterpret_cast<h16x2*>(&u);
}
__device__ __forceinline__ float clamp6(float v) { return fminf(fmaxf(v, 0.f), 6.f); }

// raw barrier: LDS-visibility only, never drains vmcnt (keeps prefetch in flight)
#define BAR_LDS()                                             \
  do {                                                        \
    asm volatile("s_waitcnt lgkmcnt(0)" ::: "memory");        \
    __builtin_amdgcn_s_barrier();                             \
  } while (0)

// ---------------------------------------------------------------------------
// K0: transpose x [b][c][y][x] f32 -> xT [b][y][x][c] bf16 (8.4 MB, in d_out).
// (unchanged; k1's MFMA path stays bf16)
// ---------------------------------------------------------------------------
__global__ __launch_bounds__(256) void k0_transpose(
    const float* __restrict__ x, unsigned short* __restrict__ xT) {
  __shared__ unsigned short xls[64][66];
  const int t = threadIdx.x;
  const int xh = blockIdx.x, y = blockIdx.y, b = blockIdx.z;
#pragma unroll
  for (int it = 0; it < 4; ++it) {
    int i = it * 256 + t;
    int xq = i & 15, c = i >> 4;
    float4 v = *reinterpret_cast<const float4*>(
        &x[((size_t)(b * CIN + c) * NH + y) * NW + xh * 64 + xq * 4]);
    *(unsigned int*)&xls[c][xq * 4]     = pack2(v.x, v.y);
    *(unsigned int*)&xls[c][xq * 4 + 2] = pack2(v.z, v.w);
  }
  __syncthreads();
#pragma unroll
  for (int it = 0; it < 4; ++it) {
    int i = it * 256 + t;
    int cq = i & 15, px = i >> 4;
    ushort4 o;
    o.x = xls[cq * 4 + 0][px];
    o.y = xls[cq * 4 + 1][px];
    o.z = xls[cq * 4 + 2][px];
    o.w = xls[cq * 4 + 3][px];
    *reinterpret_cast<ushort4*>(
        &xT[((size_t)(b * NH + y) * NW + xh * 64 + px) * 64 + cq * 4]) = o;
  }
}

// ---------------------------------------------------------------------------
// K1: per-patch pw1 (bf16 MFMA) + bn1 + relu6 -> h1T [b][y][x][hid] **fp16**.
// Only the epilogue conversion changed (pkrtz); layout/addresses identical.
// ---------------------------------------------------------------------------
__global__ __launch_bounds__(256) void k1_pw1(
    const float* __restrict__ w, const unsigned short* __restrict__ xT,
    const float* __restrict__ g1, const float* __restrict__ b1,
    const float* __restrict__ m1, const float* __restrict__ v1,
    unsigned short* __restrict__ h1T) {
  __shared__ unsigned short Wpk[2048 * 8];  // 32 KB packed A-frags

  const unsigned int id = blockIdx.x;
  const int fbq = id & 7;
  const unsigned int rest = id >> 3;
  const int hgrp = rest % 24, q = rest / 24;
  const int fb = q * 8 + fbq;
  const int f = fb & 15, b = fb >> 4;
  const int h0 = hgrp * 16;

  const int t = threadIdx.x;
  const int lane = t & 63, wv = t >> 6;
  const int quad = lane >> 4, nn = lane & 15;
  const int pxi = wv * 16 + nn;

  // ---- stage Wpk: 16 hid x 64 c x 16 g, c-paired u32 LDS writes ----
#pragma unroll
  for (int it = 0; it < 8; ++it) {
    int i = it * 256 + t;  // 0..2047
    int gq = i & 3, cp = (i >> 2) & 31, hid = i >> 7;
    const float* wp =
        &w[((size_t)b * NP + (h0 + hid) * CIN + cp * 2) * 256 + f * 16 + gq * 4];
    float4 A  = *reinterpret_cast<const float4*>(wp);
    float4 Bv = *reinterpret_cast<const float4*>(wp + 256);
    int kc = cp >> 4, qd = (cp >> 2) & 3, j = (cp & 3) * 2;
    int hs = hid ^ (2 * qd) ^ gq;
    const float* Af = (const float*)&A;
    const float* Bf = (const float*)&Bv;
#pragma unroll
    for (int k = 0; k < 4; ++k) {
      int g = gq * 4 + k;
      *(unsigned int*)&Wpk[(((g * 2 + kc) * 4 + qd) * 16 + hs) * 8 + j] =
          pack2(Af[k], Bf[k]);
    }
  }

  float iv1[4], sh1[4];
#pragma unroll
  for (int jj = 0; jj < 4; ++jj) {
    int hid = h0 + quad * 4 + jj;
    float iv = g1[hid] * rsqrtf(v1[hid] + EPSV);
    iv1[jj] = iv;
    sh1[jj] = b1[hid] - m1[hid] * iv;
  }
  __syncthreads();  // Wpk ready; read-only below

  const int y = f * 8 + (pxi >> 3);
  const size_t rowbase = ((size_t)b * NH + y) * NW;

  for (int g = 0; g < 16; ++g) {
    const int xc = g * 8 + (pxi & 7);
    const unsigned short* xp = &xT[(rowbase + xc) * 64];
    f32x4 acc = {0.f, 0.f, 0.f, 0.f};
    const int hs = nn ^ (2 * quad) ^ (g >> 2);
#pragma unroll
    for (int kc = 0; kc < 2; ++kc) {
      bf16x8 af = *reinterpret_cast<const bf16x8*>(
          &Wpk[(((g * 2 + kc) * 4 + quad) * 16 + hs) * 8]);
      bf16x8 bfr = *reinterpret_cast<const bf16x8*>(&xp[kc * 32 + quad * 8]);
      acc = __builtin_amdgcn_mfma_f32_16x16x32_bf16(af, bfr, acc, 0, 0, 0);
    }
    uint2 o;
    o.x = pkh2(clamp6(acc[0] * iv1[0] + sh1[0]),
               clamp6(acc[1] * iv1[1] + sh1[1]));
    o.y = pkh2(clamp6(acc[2] * iv1[2] + sh1[2]),
               clamp6(acc[3] * iv1[3] + sh1[3]));
    *reinterpret_cast<uint2*>(&h1T[(rowbase + xc) * HID + h0 + quad * 4]) = o;
  }
}

// ---------------------------------------------------------------------------
// K2 v5 (compile-fixed): v3's partition (512 blocks x 256 thr, 2 blocks/CU —
// measured faster than v4's merged 1 block/CU: barrier lockstep killed
// overlap) + fp16 data path. tile/k2w/h2s/W3p hold fp16; dw3 = packed
// v_pk_fma_f16 (4 ops/tap vs 24 with bf16 unpack); pw2 =
// mfma_f32_16x16x32_f16 (same frag layout, C/D dtype-independent). pkrtz
// 1-op packs replace ~9-op bf16 rounding. Accuracy improves vs bf16.
// T14 scalar prefetch pipeline unchanged (v3, WRITE_SIZE-verified no-spill).
// ---------------------------------------------------------------------------
__global__ __launch_bounds__(256, 2) void k2_fused(
    const float* __restrict__ x, const float* __restrict__ w,
    const float* __restrict__ g2, const float* __restrict__ b2v,
    const float* __restrict__ m2, const float* __restrict__ v2,
    const float* __restrict__ g3, const float* __restrict__ b3v,
    const float* __restrict__ m3, const float* __restrict__ v3,
    const unsigned short* __restrict__ h1T, float* __restrict__ out) {
  __shared__ unsigned short tile[10][34][40];  // 27.2 KB h1 halo fp16
  __shared__ unsigned short h2s[256][40];      // 20.5 KB h2 chunk fp16
  __shared__ unsigned short W3p[512 * 8];      // 8 KB packed A-frags fp16
  __shared__ unsigned short k2w[4][9][40];     // 2.9 KB dw kernels fp16
  __shared__ float iv2s[HID], sh2s[HID];       // 3 KB

  const unsigned int id = blockIdx.x;
  const int fbq = id & 7;
  const unsigned int rest = id >> 3;
  const int gang = rest & 7, q = rest >> 3;
  const int fb = q * 8 + fbq;
  const int f = fb & 15, b = fb >> 4;
  const int gq = gang >> 1, ch = gang & 1;
  const int c0 = gq * 32;

  const int t = threadIdx.x;
  const int lane = t & 63, wv = t >> 6;
  const int quad = lane >> 4, nn = lane & 15;

  for (int i = t; i < HID; i += 256) {
    float iv = g2[i] * rsqrtf(v2[i] + EPSV);
    iv2s[i] = iv;
    sh2s[i] = b2v[i] - m2[i] * iv;
  }

  float iv3[2][4], sh3[2][4];
#pragma unroll
  for (int cot = 0; cot < 2; ++cot)
#pragma unroll
    for (int jj = 0; jj < 4; ++jj) {
      int co = ch * 32 + cot * 16 + quad * 4 + jj;
      float iv = g3[co] * rsqrtf(v3[co] + EPSV);
      iv3[cot][jj] = iv;
      sh3[cot][jj] = b3v[co] - m3[co] * iv;
    }

  f32x4 acc[2][4];
#pragma unroll
  for (int cot = 0; cot < 2; ++cot)
#pragma unroll
    for (int nt = 0; nt < 4; ++nt) acc[cot][nt] = (f32x4){0.f, 0.f, 0.f, 0.f};

  const int glt = t >> 6, rt = (t >> 3) & 7, ct = t & 7;

  // ---- hoisted staging geometry, all SCALAR (chunk-invariant) ----
#define TGEOM(IDX, SRC, DST)                                          \
  {                                                                   \
    int qh = (IDX) & 3, pxid = (IDX) >> 2;                            \
    int r = pxid / 34, col = pxid - r * 34;                           \
    int yy = f * 8 - 1 + r;                                           \
    yy = (yy < 0) ? -yy : ((yy > 127) ? 254 - yy : yy);               \
    int xc = c0 - 1 + col;                                            \
    xc = (xc < 0) ? 1 : ((xc > 127) ? 126 : xc);                      \
    SRC = &h1T[(((size_t)b * NH + yy) * NW + xc) * HID + qh * 8];     \
    DST = &tile[r][col][qh * 8];                                      \
  }
  const unsigned short *ts0, *ts1, *ts2, *ts3, *ts4, *ts5;
  unsigned short *td0, *td1, *td2, *td3, *td4, *td5;
  const bool tac5 = (t < 80);
  TGEOM(t, ts0, td0);
  TGEOM(256 + t, ts1, td1);
  TGEOM(512 + t, ts2, td2);
  TGEOM(768 + t, ts3, td3);
  TGEOM(1024 + t, ts4, td4);
  {
    int idx5 = tac5 ? (1280 + t) : 1359;
    TGEOM(idx5, ts5, td5);
  }
#undef TGEOM

  // dw kernels: param index = N1 + hb*9 + i, i = hh*9+tap
  const int hh1 = t / 9, tap1 = t - hh1 * 9;
  const float* ksrc1 = &w[((size_t)b * NP + N1 + t) * 256 + f * 16 + gq * 4];
  const bool kac2 = (t < 32);
  const int i2k = 256 + t;
  const int hh2 = i2k / 9, tap2 = i2k - hh2 * 9;
  const float* ksrc2 = &w[((size_t)b * NP + N1 + i2k) * 256 + f * 16 + gq * 4];

  // W3 A-frags: 2 slots x 4 k-targets, all named scalars
  const float *wsrc0, *wsrc1;
  unsigned int *wd00, *wd01, *wd02, *wd03, *wd10, *wd11, *wd12, *wd13;
#define W3GEOM(IT, SRC, D0, D1, D2, D3)                                   \
  {                                                                      \
    int i = (IT) * 256 + t;                                              \
    int hhp = i & 15, co = i >> 4;                                       \
    SRC = &w[((size_t)b * NP + N1 + N2 + (ch * 32 + co) * HID + hhp * 2) * \
                 256 + f * 16 + gq * 4];                                 \
    int qd = (hhp * 2) >> 3, j = (hhp * 2) & 7, cot = co >> 4,           \
        cb = co & 15;                                                    \
    D0 = (unsigned int*)&W3p[(((0 * 2 + cot) * 4 + qd) * 16 +            \
                              (cb ^ (2 * qd) ^ 0)) * 8 + j];             \
    D1 = (unsigned int*)&W3p[(((1 * 2 + cot) * 4 + qd) * 16 +            \
                              (cb ^ (2 * qd) ^ 1)) * 8 + j];             \
    D2 = (unsigned int*)&W3p[(((2 * 2 + cot) * 4 + qd) * 16 +            \
                              (cb ^ (2 * qd) ^ 2)) * 8 + j];             \
    D3 = (unsigned int*)&W3p[(((3 * 2 + cot) * 4 + qd) * 16 +            \
                              (cb ^ (2 * qd) ^ 3)) * 8 + j];             \
  }
  W3GEOM(0, wsrc0, wd00, wd01, wd02, wd03);
  W3GEOM(1, wsrc1, wd10, wd11, wd12, wd13);
#undef W3GEOM

  uint4 tr0, tr1, tr2, tr3, tr4, tr5;
  float4 kr1, kr2;
  float4 wA0, wB0, wA1, wB1;

#define PREFETCH()                                                  \
  do {                                                              \
    tr0 = *reinterpret_cast<const uint4*>(ts0); ts0 += 32;          \
    tr1 = *reinterpret_cast<const uint4*>(ts1); ts1 += 32;          \
    tr2 = *reinterpret_cast<const uint4*>(ts2); ts2 += 32;          \
    tr3 = *reinterpret_cast<const uint4*>(ts3); ts3 += 32;          \
    tr4 = *reinterpret_cast<const uint4*>(ts4); ts4 += 32;          \
    if (tac5) tr5 = *reinterpret_cast<const uint4*>(ts5);           \
    ts5 += 32;                                                      \
    kr1 = *reinterpret_cast<const float4*>(ksrc1); ksrc1 += 73728;  \
    if (kac2) kr2 = *reinterpret_cast<const float4*>(ksrc2);        \
    ksrc2 += 73728;                                                 \
    wA0 = *reinterpret_cast<const float4*>(wsrc0);                  \
    wB0 = *reinterpret_cast<const float4*>(wsrc0 + 256);            \
    wsrc0 += 8192;                                                  \
    wA1 = *reinterpret_cast<const float4*>(wsrc1);                  \
    wB1 = *reinterpret_cast<const float4*>(wsrc1 + 256);            \
    wsrc1 += 8192;                                                  \
  } while (0)

  tr5 = (uint4){0u, 0u, 0u, 0u};
  kr2 = (float4){0.f, 0.f, 0.f, 0.f};
  PREFETCH();  // chunk 0

  const h16x2 hz = {(_Float16)0.f, (_Float16)0.f};

  for (int hc = 0; hc < 12; ++hc) {
    const int hb = hc * 32;
    BAR_LDS();  // prev chunk consumers done with tile/W3p/k2w/h2s

    // ---- write staged registers -> LDS ----
    *reinterpret_cast<uint4*>(td0) = tr0;
    *reinterpret_cast<uint4*>(td1) = tr1;
    *reinterpret_cast<uint4*>(td2) = tr2;
    *reinterpret_cast<uint4*>(td3) = tr3;
    *reinterpret_cast<uint4*>(td4) = tr4;
    if (tac5) *reinterpret_cast<uint4*>(td5) = tr5;
    k2w[0][tap1][hh1] = f2h(kr1.x);
    k2w[1][tap1][hh1] = f2h(kr1.y);
    k2w[2][tap1][hh1] = f2h(kr1.z);
    k2w[3][tap1][hh1] = f2h(kr1.w);
    if (kac2) {
      k2w[0][tap2][hh2] = f2h(kr2.x);
      k2w[1][tap2][hh2] = f2h(kr2.y);
      k2w[2][tap2][hh2] = f2h(kr2.z);
      k2w[3][tap2][hh2] = f2h(kr2.w);
    }
    *wd00 = pkh2(wA0.x, wB0.x);
    *wd01 = pkh2(wA0.y, wB0.y);
    *wd02 = pkh2(wA0.z, wB0.z);
    *wd03 = pkh2(wA0.w, wB0.w);
    *wd10 = pkh2(wA1.x, wB1.x);
    *wd11 = pkh2(wA1.y, wB1.y);
    *wd12 = pkh2(wA1.z, wB1.z);
    *wd13 = pkh2(wA1.w, wB1.w);

    BAR_LDS();  // LDS staged for this chunk

    // ---- issue NEXT chunk's loads; they fly under dw3 + MFMA ----
    if (hc < 11) PREFETCH();

    // ---- dw3 (packed fp16 FMA) + bn2 + relu6 -> h2s ----
#pragma unroll
    for (int hg = 0; hg < 4; ++hg) {
      h16x2 d0 = hz, d1 = hz, d2 = hz, d3 = hz;
#pragma unroll
      for (int dy = 0; dy < 3; ++dy)
#pragma unroll
        for (int dx = 0; dx < 3; ++dx) {
          const uint4 tv = *reinterpret_cast<const uint4*>(
              &tile[rt + dy][glt * 8 + ct + dx][hg * 8]);
          const uint4 kv =
              *reinterpret_cast<const uint4*>(&k2w[glt][dy * 3 + dx][hg * 8]);
          d0 += uh2(tv.x) * uh2(kv.x);
          d1 += uh2(tv.y) * uh2(kv.y);
          d2 += uh2(tv.z) * uh2(kv.z);
          d3 += uh2(tv.w) * uh2(kv.w);
        }
      const int ha = hb + hg * 8;
      uint4 o4;
      o4.x = pkh2(clamp6((float)d0[0] * iv2s[ha + 0] + sh2s[ha + 0]),
                  clamp6((float)d0[1] * iv2s[ha + 1] + sh2s[ha + 1]));
      o4.y = pkh2(clamp6((float)d1[0] * iv2s[ha + 2] + sh2s[ha + 2]),
                  clamp6((float)d1[1] * iv2s[ha + 3] + sh2s[ha + 3]));
      o4.z = pkh2(clamp6((float)d2[0] * iv2s[ha + 4] + sh2s[ha + 4]),
                  clamp6((float)d2[1] * iv2s[ha + 5] + sh2s[ha + 5]));
      o4.w = pkh2(clamp6((float)d3[0] * iv2s[ha + 6] + sh2s[ha + 6]),
                  clamp6((float)d3[1] * iv2s[ha + 7] + sh2s[ha + 7]));
      *reinterpret_cast<uint4*>(&h2s[t][hg * 8]) = o4;
    }

    BAR_LDS();  // h2s visible

    // ---- pw2 fp16 MFMA accumulate over this 32-hid chunk (wave = patch) ----
    {
      const int gl = wv;
      const int cop = nn ^ (2 * quad) ^ gl;
      f16x8 a0 = *reinterpret_cast<const f16x8*>(
          &W3p[(((gl * 2 + 0) * 4 + quad) * 16 + cop) * 8]);
      f16x8 a1 = *reinterpret_cast<const f16x8*>(
          &W3p[(((gl * 2 + 1) * 4 + quad) * 16 + cop) * 8]);
#pragma unroll
      for (int nt = 0; nt < 4; ++nt) {
        f16x8 bfr = *reinterpret_cast<const f16x8*>(
            &h2s[gl * 64 + nt * 16 + nn][quad * 8]);
        acc[0][nt] = __builtin_amdgcn_mfma_f32_16x16x32_f16(a0, bfr, acc[0][nt], 0, 0, 0);
        acc[1][nt] = __builtin_amdgcn_mfma_f32_16x16x32_f16(a1, bfr, acc[1][nt], 0, 0, 0);
      }
    }
  }

  // ---- epilogue: bn3 + residual ----
#pragma unroll
  for (int cot = 0; cot < 2; ++cot)
#pragma unroll
    for (int nt = 0; nt < 4; ++nt) {
      int pxl = nt * 16 + nn;
      int y = f * 8 + (pxl >> 3);
      int xc = c0 + wv * 8 + (pxl & 7);
#pragma unroll
      for (int jj = 0; jj < 4; ++jj) {
        int co = ch * 32 + cot * 16 + quad * 4 + jj;
        size_t adr = ((size_t)(b * COUT + co) * NH + y) * NW + xc;
        out[adr] = acc[cot][nt][jj] * iv3[cot][jj] + sh3[cot][jj] + x[adr];
      }
    }
}

extern "C" void kernel_launch(void* const* d_in, const int* in_sizes, int n_in,
                              void* d_out, int out_size, void* d_ws,
                              size_t ws_size, hipStream_t stream) {
  (void)in_sizes; (void)n_in; (void)out_size; (void)ws_size;
  const float* x  = (const float*)d_in[0];
  const float* w  = (const float*)d_in[1];
  const float* g1 = (const float*)d_in[2];
  const float* b1 = (const float*)d_in[3];
  const float* m1 = (const float*)d_in[4];
  const float* v1 = (const float*)d_in[5];
  const float* g2 = (const float*)d_in[6];
  const float* b2 = (const float*)d_in[7];
  const float* m2 = (const float*)d_in[8];
  const float* v2 = (const float*)d_in[9];
  const float* g3 = (const float*)d_in[10];
  const float* b3 = (const float*)d_in[11];
  const float* m3 = (const float*)d_in[12];
  const float* v3 = (const float*)d_in[13];
  float* out = (float*)d_out;
  unsigned short* h1T = (unsigned short*)d_ws;  // [b][y][x][hid] fp16, 50.3 MB
  unsigned short* xT = (unsigned short*)d_out;  // [b][y][x][c] bf16, 8.4 MB
                                                // (scratch; K2 overwrites out)

  k0_transpose<<<dim3(2, 128, 4), 256, 0, stream>>>(x, xT);
  k1_pw1<<<dim3(1536), 256, 0, stream>>>(w, xT, g1, b1, m1, v1, h1T);
  k2_fused<<<dim3(512), 256, 0, stream>>>(x, w, g2, b2, m2, v2, g3, b3, m3, v3,
                                          h1T, out);
}